// Round 4
// baseline (123.558 us; speedup 1.0000x reference)
//
#include <hip/hip_runtime.h>

#define B_ 2
#define L_ 256
#define D_ 512
#define H_ 8
#define DV_ 64
#define NEGINF 1e12f

// ws layout (floats):
#define WS_VALUE 0
#define WS_WR    262144
#define WS_SSRC  266240
#define WS_STGT  270336

#define GLOAD_LDS16(g, l)                                                     \
    __builtin_amdgcn_global_load_lds(                                         \
        (const __attribute__((address_space(1))) void*)(g),                   \
        (__attribute__((address_space(3))) void*)(l), 16, 0, 0)

// ---------------- Kernel A: WR[k][h] = sum_d W_relation[k][h*64+d] * w_rel[h][d]
__global__ __launch_bounds__(256) void k_wr(const float* __restrict__ Wrel,
                                            const float* __restrict__ wrel,
                                            float* __restrict__ WR) {
    int flat = blockIdx.x * 256 + threadIdx.x;   // 4096 = 512*8
    int k = flat >> 3, h = flat & 7;
    const float* a = Wrel + k * 512 + h * 64;
    const float* b = wrel + h * 64;
    float s = 0.f;
#pragma unroll
    for (int d = 0; d < 64; d += 4) {
        float4 x = *(const float4*)(a + d);
        float4 y = *(const float4*)(b + d);
        s += x.x * y.x + x.y * y.y + x.z * y.z + x.w * y.w;
    }
    WR[k * 8 + h] = s;
}

// ---------------- Kernel B: value[b][h][l][dv] = sum_k inp[b][l][k] * W_value[k][h*64+dv]
__global__ __launch_bounds__(256) void k_value(const float* __restrict__ inp,
                                               const float* __restrict__ Wv,
                                               float* __restrict__ value) {
    int blk = blockIdx.x;          // 256 blocks = 128 row-tiles x 2 col-halves
    int ct  = blk & 1;
    int rt  = blk >> 1;
    int n   = ct * 256 + threadIdx.x;   // output col 0..511
    int r0  = rt * 4;
    const float* i0 = inp + (size_t)(r0 + 0) * 512;
    const float* i1 = inp + (size_t)(r0 + 1) * 512;
    const float* i2 = inp + (size_t)(r0 + 2) * 512;
    const float* i3 = inp + (size_t)(r0 + 3) * 512;
    float a0 = 0.f, a1 = 0.f, a2 = 0.f, a3 = 0.f;
#pragma unroll 16
    for (int k = 0; k < 512; ++k) {
        float w = Wv[(size_t)k * 512 + n];
        a0 = fmaf(i0[k], w, a0);
        a1 = fmaf(i1[k], w, a1);
        a2 = fmaf(i2[k], w, a2);
        a3 = fmaf(i3[k], w, a3);
    }
    int h = n >> 6, dv = n & 63;
    float acc[4] = {a0, a1, a2, a3};
#pragma unroll
    for (int r = 0; r < 4; ++r) {
        int row = r0 + r;
        int b = row >> 8, l = row & 255;
        value[(((size_t)(b * 8 + h)) * 256 + l) * 64 + dv] = acc[r];
    }
}

// ---------------- Kernel C: s_src/s_tgt[b][h][j] = dot(value[b][h][j][:], w_{src,tgt}[h][:])
__global__ __launch_bounds__(256) void k_src_tgt(const float* __restrict__ value,
                                                 const float* __restrict__ wsrc,
                                                 const float* __restrict__ wtgt,
                                                 float* __restrict__ s_src,
                                                 float* __restrict__ s_tgt) {
    int flat = blockIdx.x * 256 + threadIdx.x;   // 4096 = (b*8+h)*256 + j
    int h = (flat >> 8) & 7;
    const float* v  = value + (size_t)flat * 64;
    const float* ws = wsrc + h * 64;
    const float* wt = wtgt + h * 64;
    float ss = 0.f, st = 0.f;
#pragma unroll
    for (int d = 0; d < 64; d += 4) {
        float4 x = *(const float4*)(v + d);
        float4 s4 = *(const float4*)(ws + d);
        float4 t4 = *(const float4*)(wt + d);
        ss += x.x * s4.x + x.y * s4.y + x.z * s4.z + x.w * s4.w;
        st += x.x * t4.x + x.y * t4.y + x.z * t4.z + x.w * t4.w;
    }
    s_src[flat] = ss;
    s_tgt[flat] = st;
}

// ---------------- Kernel D: fused s_rel + softmax + out
// Block = one (b,i). 256 threads, thread t owns j-row t.
// Phase 1: barrier-free double-buffered global_load_lds pipeline.
//   16 k-tiles of width 32 floats (128 B/row). Wave w stages exactly rows
//   [64w,64w+64) = the rows its own threads read -> no cross-wave dep, only
//   per-wave counted vmcnt. XOR bank swizzle applied on the per-lane GLOBAL
//   source address (LDS dest must stay linear for global_load_lds).
__global__ __launch_bounds__(256) void k_main(const float* __restrict__ rel,    // [bi][j][k]
                                              const int*   __restrict__ mask,   // [bi][j]
                                              const float* __restrict__ adj,    // [b][h][i][j]
                                              const float* __restrict__ inp,    // [bi][D]
                                              const float* __restrict__ value,  // [b][h][j][dv]
                                              const float* __restrict__ WR,     // [k][h]
                                              const float* __restrict__ s_src,  // [b][h][j]
                                              const float* __restrict__ s_tgt,  // [b][h][i]
                                              float* __restrict__ out) {        // [bi][D]
    __shared__ float lds[16384];       // 64 KB: two 32KB k-tile buffers
    int bi   = blockIdx.x;
    int b    = bi >> 8;
    int i    = bi & 255;
    int tid  = threadIdx.x;
    int w    = tid >> 6;               // wave 0..3
    int lane = tid & 63;

    const float* relbase = rel + (size_t)bi * 256 * 512;

    // Per-lane fixed staging geometry: slot f = w*512 + s*64 + lane,
    // row r = f>>3, chunk c = f&7, swizzled chunk c' = c ^ (r&7).
    // Precompute per-lane global byte offsets for the 8 staging instrs.
    const float* gsrc[8];
    {
#pragma unroll
        for (int s = 0; s < 8; ++s) {
            int f = w * 512 + s * 64 + lane;
            int r = f >> 3, c = f & 7;
            int cp = c ^ (r & 7);
            gsrc[s] = relbase + (size_t)r * 512 + cp * 4;   // + k0 at issue
        }
    }

#define STAGE(bufofs, k0)                                                      \
    {                                                                          \
        _Pragma("unroll")                                                      \
        for (int s = 0; s < 8; ++s)                                            \
            GLOAD_LDS16(gsrc[s] + (k0), &lds[(bufofs) + w * 2048 + s * 256]);  \
    }

    float acc[8];
#pragma unroll
    for (int h = 0; h < 8; ++h) acc[h] = 0.f;

    // my row's LDS base (float idx): row t occupies slots t*8.. -> floats t*32..
    int tswz = tid & 7;

    STAGE(0, 0);                       // prologue: tile 0 -> buf0
    for (int kt = 0; kt < 16; ++kt) {
        int cur = (kt & 1) * 8192;
        if (kt < 15) {
            int nxt = ((kt + 1) & 1) * 8192;
            STAGE(nxt, (kt + 1) * 32);
            asm volatile("s_waitcnt vmcnt(8)" ::: "memory");
        } else {
            asm volatile("s_waitcnt vmcnt(0)" ::: "memory");
        }
        const float* myrow = &lds[cur + tid * 32];
        const float* wrt   = WR + kt * 32 * 8;   // wave-uniform -> s_load
#pragma unroll
        for (int q = 0; q < 8; ++q) {
            float4 x = *(const float4*)&myrow[(q ^ tswz) << 2];
#pragma unroll
            for (int h = 0; h < 8; ++h) {
                acc[h] = fmaf(x.x, wrt[(q * 4 + 0) * 8 + h],
                         fmaf(x.y, wrt[(q * 4 + 1) * 8 + h],
                         fmaf(x.z, wrt[(q * 4 + 2) * 8 + h],
                         fmaf(x.w, wrt[(q * 4 + 3) * 8 + h], acc[h]))));
            }
        }
    }

    // publish srel into lds[0..2047] (overlaps wave partitions -> barrier first)
    __syncthreads();
    float* srel_s = lds;               // [h][j]
    float* attn_s = lds + 2048;        // [h][j]
#pragma unroll
    for (int h = 0; h < 8; ++h) srel_s[h * 256 + tid] = acc[h];
    __syncthreads();

    // ---- Phase 2: per-h row softmax over j; 32 lanes per h, 8 j per lane
    {
        int h  = tid >> 5;
        int ln = tid & 31;
        float stgt = s_tgt[(size_t)(b * 8 + h) * 256 + i];
        const float* ssrc   = s_src + (size_t)(b * 8 + h) * 256;
        const float* adjrow = adj + ((size_t)(b * 8 + h) * 256 + i) * 256;
        const int*   mrow   = mask + (size_t)bi * 256;

        float sc[8], av[8];
        int mb = 0;
        float rowmax = -3.0e38f;
#pragma unroll
        for (int t = 0; t < 8; ++t) {
            int j = ln + 32 * t;
            float a = adjrow[j];
            av[t] = a;
            int m = mrow[j];
            float s = ssrc[j] + stgt + srel_s[h * 256 + j];
            s = (s >= 0.f) ? s : 0.2f * s;     // leaky relu
            if (m != 0) { s = -NEGINF; mb |= (1 << t); }
            if (a == 0.f) s = -NEGINF;
            sc[t] = s;
            rowmax = fmaxf(rowmax, s);
        }
#pragma unroll
        for (int off = 16; off >= 1; off >>= 1)
            rowmax = fmaxf(rowmax, __shfl_xor(rowmax, off));

        float rowsum = 0.f;
#pragma unroll
        for (int t = 0; t < 8; ++t) {
            sc[t] = expf(sc[t] - rowmax);
            rowsum += sc[t];
        }
#pragma unroll
        for (int off = 16; off >= 1; off >>= 1)
            rowsum += __shfl_xor(rowsum, off);

        float sumabs = 0.f;
#pragma unroll
        for (int t = 0; t < 8; ++t) {
            float p = sc[t] / rowsum;
            float invv = (av[t] == 0.f) ? 1e-12f : (1.0f / av[t]);
            p *= invv;
            sc[t] = p;
            sumabs += fabsf(p);
        }
#pragma unroll
        for (int off = 16; off >= 1; off >>= 1)
            sumabs += __shfl_xor(sumabs, off);

        float rdn = 1.0f / fmaxf(sumabs, 1e-12f);
#pragma unroll
        for (int t = 0; t < 8; ++t) {
            float p = sc[t] * rdn;
            if (mb & (1 << t)) p = 0.f;
            if (av[t] == 0.f) p = 0.f;
            attn_s[h * 256 + ln + 32 * t] = p;
        }
    }
    __syncthreads();

    // ---- Phase 3: out[bi][h*64+d] = inp + sum_j attn[h][j] * value[b][h][j][d]
    {
        int h  = tid >> 5;
        int d0 = (tid & 31) * 2;
        const float* vbase = value + ((size_t)(b * 8 + h) * 256) * 64 + d0;
        const float* arow  = attn_s + h * 256;
        float ax = 0.f, ay = 0.f;
#pragma unroll 4
        for (int j = 0; j < 256; ++j) {
            float a = arow[j];
            float2 v2 = *(const float2*)(vbase + (size_t)j * 64);
            ax = fmaf(a, v2.x, ax);
            ay = fmaf(a, v2.y, ay);
        }
        size_t o = (size_t)bi * 512 + h * 64 + d0;
        out[o]     = inp[o] + ax;
        out[o + 1] = inp[o + 1] + ay;
    }
}

extern "C" void kernel_launch(void* const* d_in, const int* in_sizes, int n_in,
                              void* d_out, int out_size, void* d_ws, size_t ws_size,
                              hipStream_t stream) {
    const float* inp      = (const float*)d_in[0];
    const float* rel      = (const float*)d_in[1];
    const int*   mask     = (const int*)  d_in[2];
    const float* adj      = (const float*)d_in[3];
    const float* W_value  = (const float*)d_in[4];
    const float* W_rel    = (const float*)d_in[5];
    const float* w_src    = (const float*)d_in[6];
    const float* w_tgt    = (const float*)d_in[7];
    const float* w_rel    = (const float*)d_in[8];
    float* out = (float*)d_out;

    float* ws    = (float*)d_ws;
    float* value = ws + WS_VALUE;
    float* WR    = ws + WS_WR;
    float* s_src = ws + WS_SSRC;
    float* s_tgt = ws + WS_STGT;

    k_wr<<<16, 256, 0, stream>>>(W_rel, w_rel, WR);
    k_value<<<256, 256, 0, stream>>>(inp, W_value, value);
    k_src_tgt<<<16, 256, 0, stream>>>(value, w_src, w_tgt, s_src, s_tgt);
    k_main<<<B_ * L_, 256, 0, stream>>>(rel, mask, adj, inp, value, WR,
                                        s_src, s_tgt, out);
}

// Round 5
// 118.426 us; speedup vs baseline: 1.0433x; 1.0433x over previous
//
#include <hip/hip_runtime.h>

#define B_ 2
#define L_ 256
#define D_ 512
#define H_ 8
#define DV_ 64
#define NEGINF 1e12f

// ws layout (floats):
#define WS_VALUE 0
#define WS_WR    262144
#define WS_SSRC  266240
#define WS_STGT  270336

#define GLOAD_LDS16(g, l)                                                     \
    __builtin_amdgcn_global_load_lds(                                         \
        (const __attribute__((address_space(1))) void*)(g),                   \
        (__attribute__((address_space(3))) void*)(l), 16, 0, 0)

// ---------------- Kernel A: WR[k][h] = sum_d W_relation[k][h*64+d] * w_rel[h][d]
__global__ __launch_bounds__(256) void k_wr(const float* __restrict__ Wrel,
                                            const float* __restrict__ wrel,
                                            float* __restrict__ WR) {
    int flat = blockIdx.x * 256 + threadIdx.x;   // 4096 = 512*8
    int k = flat >> 3, h = flat & 7;
    const float* a = Wrel + k * 512 + h * 64;
    const float* b = wrel + h * 64;
    float s = 0.f;
#pragma unroll
    for (int d = 0; d < 64; d += 4) {
        float4 x = *(const float4*)(a + d);
        float4 y = *(const float4*)(b + d);
        s += x.x * y.x + x.y * y.y + x.z * y.z + x.w * y.w;
    }
    WR[k * 8 + h] = s;
}

// ---------------- Kernel B: value = inp @ W_value, + fused s_src/s_tgt epilogue
// Each wave covers exactly one head's 64 output cols -> butterfly reduce.
__global__ __launch_bounds__(256) void k_value(const float* __restrict__ inp,
                                               const float* __restrict__ Wv,
                                               const float* __restrict__ wsrc,
                                               const float* __restrict__ wtgt,
                                               float* __restrict__ value,
                                               float* __restrict__ s_src,
                                               float* __restrict__ s_tgt) {
    int blk = blockIdx.x;          // 256 blocks = 128 row-tiles x 2 col-halves
    int ct  = blk & 1;
    int rt  = blk >> 1;
    int n   = ct * 256 + threadIdx.x;   // output col 0..511
    int r0  = rt * 4;
    const float* i0 = inp + (size_t)(r0 + 0) * 512;
    const float* i1 = inp + (size_t)(r0 + 1) * 512;
    const float* i2 = inp + (size_t)(r0 + 2) * 512;
    const float* i3 = inp + (size_t)(r0 + 3) * 512;
    float a0 = 0.f, a1 = 0.f, a2 = 0.f, a3 = 0.f;
#pragma unroll 16
    for (int k = 0; k < 512; ++k) {
        float w = Wv[(size_t)k * 512 + n];
        a0 = fmaf(i0[k], w, a0);
        a1 = fmaf(i1[k], w, a1);
        a2 = fmaf(i2[k], w, a2);
        a3 = fmaf(i3[k], w, a3);
    }
    int h = n >> 6, dv = n & 63;
    float acc[4] = {a0, a1, a2, a3};
    float wsv = wsrc[h * 64 + dv];
    float wtv = wtgt[h * 64 + dv];
#pragma unroll
    for (int r = 0; r < 4; ++r) {
        int row = r0 + r;
        int b = row >> 8, l = row & 255;
        value[(((size_t)(b * 8 + h)) * 256 + l) * 64 + dv] = acc[r];
        // fused s_src/s_tgt: reduce acc[r]*w over the wave's 64 lanes (= dv axis)
        float ss = acc[r] * wsv;
        float st = acc[r] * wtv;
#pragma unroll
        for (int off = 32; off >= 1; off >>= 1) {
            ss += __shfl_xor(ss, off);
            st += __shfl_xor(st, off);
        }
        if (dv == 0) {
            s_src[(size_t)(b * 8 + h) * 256 + l] = ss;
            s_tgt[(size_t)(b * 8 + h) * 256 + l] = st;
        }
    }
}

// ---------------- Kernel D: fused s_rel + softmax + out
// Block = one (b,i). 256 threads, thread t owns j-row t.
// kw=16 double-buffered (32 KB LDS -> 4 blocks/CU), barrier-free wave-private
// gload_lds pipeline: wave w stages rows [64w,64w+64), counted vmcnt(4).
__global__ __launch_bounds__(256) void k_main(const float* __restrict__ rel,    // [bi][j][k]
                                              const int*   __restrict__ mask,   // [bi][j]
                                              const float* __restrict__ adj,    // [b][h][i][j]
                                              const float* __restrict__ inp,    // [bi][D]
                                              const float* __restrict__ value,  // [b][h][j][dv]
                                              const float* __restrict__ WR,     // [k][h]
                                              const float* __restrict__ s_src,  // [b][h][j]
                                              const float* __restrict__ s_tgt,  // [b][h][i]
                                              float* __restrict__ out) {        // [bi][D]
    __shared__ float lds[8192];        // 32 KB: two 16 KB k-tile buffers
    int bi   = blockIdx.x;
    int b    = bi >> 8;
    int i    = bi & 255;
    int tid  = threadIdx.x;
    int w    = tid >> 6;               // wave 0..3
    int lane = tid & 63;

    const float* relbase = rel + (size_t)bi * 256 * 512;

    // Staging geometry (kw=16 floats/row): wave slot f = s*64 + lane (s=0..3),
    // r_local = f>>2, chunk c = f&3, global row r = w*64 + r_local,
    // swizzled chunk c' = c ^ (r&3). LDS dest linear; swizzle on global src.
    const float* gsrc[4];
    {
#pragma unroll
        for (int s = 0; s < 4; ++s) {
            int f = s * 64 + lane;
            int rl = f >> 2, c = f & 3;
            int r = w * 64 + rl;
            int cp = c ^ (r & 3);
            gsrc[s] = relbase + (size_t)r * 512 + cp * 4;   // + k0 at issue
        }
    }

#define STAGE(bufofs, k0)                                                      \
    {                                                                          \
        _Pragma("unroll")                                                      \
        for (int s = 0; s < 4; ++s)                                            \
            GLOAD_LDS16(gsrc[s] + (k0), &lds[(bufofs) + w * 1024 + s * 256]);  \
    }

    float acc[8];
#pragma unroll
    for (int h = 0; h < 8; ++h) acc[h] = 0.f;

    int tswz = tid & 3;

    STAGE(0, 0);                       // prologue: tile 0 -> buf0
    for (int kt = 0; kt < 32; ++kt) {
        int cur = (kt & 1) * 4096;
        if (kt < 31) {
            int nxt = ((kt + 1) & 1) * 4096;
            STAGE(nxt, (kt + 1) * 16);
            asm volatile("s_waitcnt vmcnt(4)" ::: "memory");
        } else {
            asm volatile("s_waitcnt vmcnt(0)" ::: "memory");
        }
        const float* myrow = &lds[cur + tid * 16];
        const float* wrt   = WR + kt * 16 * 8;   // wave-uniform -> s_load
#pragma unroll
        for (int q = 0; q < 4; ++q) {
            float4 x = *(const float4*)&myrow[(q ^ tswz) << 2];
#pragma unroll
            for (int h = 0; h < 8; ++h) {
                acc[h] = fmaf(x.x, wrt[(q * 4 + 0) * 8 + h],
                         fmaf(x.y, wrt[(q * 4 + 1) * 8 + h],
                         fmaf(x.z, wrt[(q * 4 + 2) * 8 + h],
                         fmaf(x.w, wrt[(q * 4 + 3) * 8 + h], acc[h]))));
            }
        }
    }

    // publish srel into lds[0..2047] (overlaps wave partitions -> barrier first)
    __syncthreads();
    float* srel_s = lds;               // [h][j]
    float* attn_s = lds + 2048;        // [h][j]
#pragma unroll
    for (int h = 0; h < 8; ++h) srel_s[h * 256 + tid] = acc[h];
    __syncthreads();

    // ---- Phase 2: per-h row softmax over j; 32 lanes per h, 8 j per lane
    {
        int h  = tid >> 5;
        int ln = tid & 31;
        float stgt = s_tgt[(size_t)(b * 8 + h) * 256 + i];
        const float* ssrc   = s_src + (size_t)(b * 8 + h) * 256;
        const float* adjrow = adj + ((size_t)(b * 8 + h) * 256 + i) * 256;
        const int*   mrow   = mask + (size_t)bi * 256;

        float sc[8], av[8];
        int mb = 0;
        float rowmax = -3.0e38f;
#pragma unroll
        for (int t = 0; t < 8; ++t) {
            int j = ln + 32 * t;
            float a = adjrow[j];
            av[t] = a;
            int m = mrow[j];
            float s = ssrc[j] + stgt + srel_s[h * 256 + j];
            s = (s >= 0.f) ? s : 0.2f * s;     // leaky relu
            if (m != 0) { s = -NEGINF; mb |= (1 << t); }
            if (a == 0.f) s = -NEGINF;
            sc[t] = s;
            rowmax = fmaxf(rowmax, s);
        }
#pragma unroll
        for (int off = 16; off >= 1; off >>= 1)
            rowmax = fmaxf(rowmax, __shfl_xor(rowmax, off));

        float rowsum = 0.f;
#pragma unroll
        for (int t = 0; t < 8; ++t) {
            sc[t] = expf(sc[t] - rowmax);
            rowsum += sc[t];
        }
#pragma unroll
        for (int off = 16; off >= 1; off >>= 1)
            rowsum += __shfl_xor(rowsum, off);

        float sumabs = 0.f;
#pragma unroll
        for (int t = 0; t < 8; ++t) {
            float p = sc[t] / rowsum;
            float invv = (av[t] == 0.f) ? 1e-12f : (1.0f / av[t]);
            p *= invv;
            sc[t] = p;
            sumabs += fabsf(p);
        }
#pragma unroll
        for (int off = 16; off >= 1; off >>= 1)
            sumabs += __shfl_xor(sumabs, off);

        float rdn = 1.0f / fmaxf(sumabs, 1e-12f);
#pragma unroll
        for (int t = 0; t < 8; ++t) {
            float p = sc[t] * rdn;
            if (mb & (1 << t)) p = 0.f;
            if (av[t] == 0.f) p = 0.f;
            attn_s[h * 256 + ln + 32 * t] = p;
        }
    }
    __syncthreads();

    // ---- Phase 3: out[bi][h*64+d] = inp + sum_j attn[h][j] * value[b][h][j][d]
    {
        int h  = tid >> 5;
        int d0 = (tid & 31) * 2;
        const float* vbase = value + ((size_t)(b * 8 + h) * 256) * 64 + d0;
        const float* arow  = attn_s + h * 256;
        float ax = 0.f, ay = 0.f;
#pragma unroll 8
        for (int j = 0; j < 256; ++j) {
            float a = arow[j];
            float2 v2 = *(const float2*)(vbase + (size_t)j * 64);
            ax = fmaf(a, v2.x, ax);
            ay = fmaf(a, v2.y, ay);
        }
        size_t o = (size_t)bi * 512 + h * 64 + d0;
        out[o]     = inp[o] + ax;
        out[o + 1] = inp[o + 1] + ay;
    }
}

extern "C" void kernel_launch(void* const* d_in, const int* in_sizes, int n_in,
                              void* d_out, int out_size, void* d_ws, size_t ws_size,
                              hipStream_t stream) {
    const float* inp      = (const float*)d_in[0];
    const float* rel      = (const float*)d_in[1];
    const int*   mask     = (const int*)  d_in[2];
    const float* adj      = (const float*)d_in[3];
    const float* W_value  = (const float*)d_in[4];
    const float* W_rel    = (const float*)d_in[5];
    const float* w_src    = (const float*)d_in[6];
    const float* w_tgt    = (const float*)d_in[7];
    const float* w_rel    = (const float*)d_in[8];
    float* out = (float*)d_out;

    float* ws    = (float*)d_ws;
    float* value = ws + WS_VALUE;
    float* WR    = ws + WS_WR;
    float* s_src = ws + WS_SSRC;
    float* s_tgt = ws + WS_STGT;

    k_wr<<<16, 256, 0, stream>>>(W_rel, w_rel, WR);
    k_value<<<256, 256, 0, stream>>>(inp, W_value, w_src, w_tgt,
                                     value, s_src, s_tgt);
    k_main<<<B_ * L_, 256, 0, stream>>>(rel, mask, adj, inp, value, WR,
                                        s_src, s_tgt, out);
}